// Round 6
// baseline (592.109 us; speedup 1.0000x reference)
//
#include <hip/hip_runtime.h>
#include <math.h>

// GraphSage GNN forward. N=100000 (div 32), E=600000, HID=128, OUT=40, G=64, L=3.
// R6 = R5 (gather fused into GEMM A-staging) + ping-pong h buffers to fix the
// cross-block read/write race (hin must not alias hout when gathering neighbors).

typedef __bf16 bf16;
typedef __bf16 bf16x4 __attribute__((ext_vector_type(4)));
typedef __bf16 bf16x8 __attribute__((ext_vector_type(8)));
typedef float  f32x4  __attribute__((ext_vector_type(4)));

static inline size_t alignup(size_t x){ return (x + 255) & ~(size_t)255; }

// ---------------- CSR build ----------------
__global__ void count_kernel(const int* __restrict__ ei, int E, int* __restrict__ cnt){
  int e = blockIdx.x*256 + threadIdx.x;
  if (e < E) atomicAdd(&cnt[ei[E + e]], 1);   // dst row
}

__global__ void scan1_kernel(const int* __restrict__ cnt, int* __restrict__ rs,
                             int* __restrict__ bsum, int N){
  __shared__ int s[256];
  int t = threadIdx.x;
  int i = blockIdx.x*256 + t;
  int v = (i < N) ? cnt[i] : 0;
  s[t] = v; __syncthreads();
  for (int off = 1; off < 256; off <<= 1){
    int x = (t >= off) ? s[t-off] : 0;
    __syncthreads();
    s[t] += x;
    __syncthreads();
  }
  if (i < N) rs[i] = s[t] - v;
  if (t == 255) bsum[blockIdx.x] = s[255];
}

__global__ void scan2_kernel(int* __restrict__ bsum, int NB){
  __shared__ int s[512];
  int t = threadIdx.x;
  int v = (t < NB) ? bsum[t] : 0;
  s[t] = v; __syncthreads();
  for (int off = 1; off < 512; off <<= 1){
    int x = (t >= off) ? s[t-off] : 0;
    __syncthreads();
    s[t] += x;
    __syncthreads();
  }
  if (t < NB) bsum[t] = s[t] - v;
}

__global__ void scan3_kernel(int* __restrict__ rs, const int* __restrict__ bsum,
                             int* __restrict__ cur, int N){
  int i = blockIdx.x*256 + threadIdx.x;
  if (i < N){
    int v = rs[i] + bsum[blockIdx.x];
    rs[i] = v;
    cur[i] = v;
  }
}

__global__ void fill_kernel(const int* __restrict__ ei, int E, int* __restrict__ cur,
                            int* __restrict__ esrc){
  int e = blockIdx.x*256 + threadIdx.x;
  if (e < E){
    int d = ei[E + e];
    int p = atomicAdd(&cur[d], 1);
    esrc[p] = ei[e];
  }
}

// ---------------- x -> bf16 ----------------
__global__ void xbf_kernel(const float* __restrict__ x, bf16* __restrict__ xb, int total8){
  int i = blockIdx.x*256 + threadIdx.x;
  if (i < total8){
    float4 a = *(const float4*)(x + (size_t)i*8);
    float4 b = *(const float4*)(x + (size_t)i*8 + 4);
    bf16x8 o;
    o[0]=(bf16)a.x; o[1]=(bf16)a.y; o[2]=(bf16)a.z; o[3]=(bf16)a.w;
    o[4]=(bf16)b.x; o[5]=(bf16)b.y; o[6]=(bf16)b.z; o[7]=(bf16)b.w;
    *(bf16x8*)(xb + (size_t)i*8) = o;
  }
}

// ---------------- collapsed postMP weights: Wc = W2@W1 (40x128), bc = W2@b1 + b2 ----------------
__global__ void wc_kernel(const float* __restrict__ W1, const float* __restrict__ b1,
                          const float* __restrict__ W2, const float* __restrict__ b2,
                          float* __restrict__ Wc, float* __restrict__ bc){
  int o = blockIdx.x;        // 0..39
  int k = threadIdx.x;       // 0..127
  float s = 0.0f;
  for (int j = 0; j < 128; ++j) s = fmaf(W2[o*128 + j], W1[j*128 + k], s);
  Wc[o*128 + k] = s;
  __shared__ float r[128];
  r[k] = W2[o*128 + k] * b1[k];
  __syncthreads();
  for (int off = 64; off; off >>= 1){
    if (k < off) r[k] += r[k + off];
    __syncthreads();
  }
  if (k == 0) bc[o] = r[0] + b2[o];
}

// ---------------- weight prep: Wbig[l][c][k], k<128 -> Wl[l][c][k], k>=128 -> Wr[l][c][k-128]
__global__ void wprep_kernel(const float* __restrict__ Wl, const float* __restrict__ Wr,
                             bf16* __restrict__ Wbig){
  int idx = blockIdx.x*256 + threadIdx.x;
  if (idx < 3*128*256){
    int l = idx / 32768, rem = idx % 32768, c = rem >> 8, k = rem & 255;
    float w = (k < 128) ? Wl[l*16384 + c*128 + k] : Wr[l*16384 + c*128 + (k-128)];
    Wbig[idx] = (bf16)w;
  }
}

// ---------------- fused layer kernel:
// stage A = [act(h_row) | mean_{j in N(row)} act(h_j)] (32 x 256) via CSR walk,
// MFMA K=256 -> h2, deg-0 br fix, row L2-norm, store bf16, BN stats in regs.
// NOTE: hin and hout MUST NOT alias (neighbor gather reads arbitrary rows).
__global__ __launch_bounds__(256, 2) void gemm_fused(
    const bf16* __restrict__ hin, const float* __restrict__ bnp, int use_act,
    const bf16* __restrict__ Wbig, const float* __restrict__ bl, const float* __restrict__ br,
    const int* __restrict__ rs, const int* __restrict__ cnt, const int* __restrict__ esrc,
    bf16* __restrict__ hout, float* __restrict__ colstats, int N)
{
  __shared__ bf16 alds[32*256];     // 16 KB, XOR-swizzled 16B chunks (chunk ^ (row&7))
  __shared__ float rowsq_w[4][32];  // per-wave row sq-partials
  const int t = threadIdx.x;
  const int wv = t >> 6, lane = t & 63;
  const int quad = lane >> 4, l16 = lane & 15;
  const int cbase = wv * 32;
  const int row8 = t >> 3, tid8 = t & 7;   // staging: 8 threads per dst row

  // W fragments in registers: wreg[nt][ks]
  bf16x8 wreg[2][8];
  #pragma unroll
  for (int nt = 0; nt < 2; ++nt){
    const bf16* wp = Wbig + (size_t)(cbase + nt*16 + l16) * 256 + quad*8;
    #pragma unroll
    for (int ks = 0; ks < 8; ++ks)
      wreg[nt][ks] = *(const bf16x8*)(wp + ks*32);
  }
  float biasv[2][4], brv[2][4];
  #pragma unroll
  for (int nt = 0; nt < 2; ++nt){
    int c0 = cbase + nt*16 + quad*4;
    float4 b4 = *(const float4*)(bl + c0);
    float4 r4 = *(const float4*)(br + c0);
    biasv[nt][0] = b4.x + r4.x; biasv[nt][1] = b4.y + r4.y;
    biasv[nt][2] = b4.z + r4.z; biasv[nt][3] = b4.w + r4.w;
    brv[nt][0] = r4.x; brv[nt][1] = r4.y; brv[nt][2] = r4.z; brv[nt][3] = r4.w;
  }
  // act params for this thread's two col-slices (tid8*8 and 64+tid8*8)
  float scA[8], shA[8], scB[8], shB[8];
  if (use_act){
    *(float4*)(scA)   = *(const float4*)(bnp + tid8*8);
    *(float4*)(scA+4) = *(const float4*)(bnp + tid8*8 + 4);
    *(float4*)(scB)   = *(const float4*)(bnp + 64 + tid8*8);
    *(float4*)(scB+4) = *(const float4*)(bnp + 64 + tid8*8 + 4);
    *(float4*)(shA)   = *(const float4*)(bnp + 128 + tid8*8);
    *(float4*)(shA+4) = *(const float4*)(bnp + 128 + tid8*8 + 4);
    *(float4*)(shB)   = *(const float4*)(bnp + 192 + tid8*8);
    *(float4*)(shB+4) = *(const float4*)(bnp + 192 + tid8*8 + 4);
  }
  // register-accumulated BN column stats
  float cs_acc[2][4] = {{0,0,0,0},{0,0,0,0}};
  float cq_acc[2][4] = {{0,0,0,0},{0,0,0,0}};

  const int swz = (row8 & 7);
  bf16* dst0 = alds + row8*256 + ((tid8      ^ swz) * 8);
  bf16* dst1 = alds + row8*256 + (((8+tid8)  ^ swz) * 8);
  bf16* dst2 = alds + row8*256 + (((16+tid8) ^ swz) * 8);
  bf16* dst3 = alds + row8*256 + (((24+tid8) ^ swz) * 8);

  const int ntiles = N >> 5;   // N % 32 == 0
  for (int tile = blockIdx.x; tile < ntiles; tile += gridDim.x){
    const int rbase = tile << 5;
    const int grow = rbase + row8;
    // ---- own row: act(h[grow]) -> cols 0..127 ----
    {
      const bf16* src = hin + (size_t)grow*128;
      bf16x8 v0 = *(const bf16x8*)(src + tid8*8);
      bf16x8 v1 = *(const bf16x8*)(src + 64 + tid8*8);
      if (use_act){
        #pragma unroll
        for (int j = 0; j < 8; ++j){
          v0[j] = (bf16)fmaxf(fmaf((float)v0[j], scA[j], shA[j]), 0.0f);
          v1[j] = (bf16)fmaxf(fmaf((float)v1[j], scB[j], shB[j]), 0.0f);
        }
      }
      *(bf16x8*)dst0 = v0;
      *(bf16x8*)dst1 = v1;
    }
    // ---- gather: mean of act(h[src]) over CSR list -> cols 128..255 ----
    {
      const int start = rs[grow];
      const int c = cnt[grow];
      float agA[8], agB[8];
      #pragma unroll
      for (int j = 0; j < 8; ++j){ agA[j] = 0.f; agB[j] = 0.f; }
      int e = 0;
      for (; e + 2 <= c; e += 2){
        int s0 = esrc[start + e];
        int s1 = esrc[start + e + 1];
        bf16x8 u0 = *(const bf16x8*)(hin + (size_t)s0*128 + tid8*8);
        bf16x8 u1 = *(const bf16x8*)(hin + (size_t)s0*128 + 64 + tid8*8);
        bf16x8 u2 = *(const bf16x8*)(hin + (size_t)s1*128 + tid8*8);
        bf16x8 u3 = *(const bf16x8*)(hin + (size_t)s1*128 + 64 + tid8*8);
        if (use_act){
          #pragma unroll
          for (int j = 0; j < 8; ++j){
            agA[j] += fmaxf(fmaf((float)u0[j], scA[j], shA[j]), 0.f)
                    + fmaxf(fmaf((float)u2[j], scA[j], shA[j]), 0.f);
            agB[j] += fmaxf(fmaf((float)u1[j], scB[j], shB[j]), 0.f)
                    + fmaxf(fmaf((float)u3[j], scB[j], shB[j]), 0.f);
          }
        } else {
          #pragma unroll
          for (int j = 0; j < 8; ++j){
            agA[j] += (float)u0[j] + (float)u2[j];
            agB[j] += (float)u1[j] + (float)u3[j];
          }
        }
      }
      if (e < c){
        int s0 = esrc[start + e];
        bf16x8 u0 = *(const bf16x8*)(hin + (size_t)s0*128 + tid8*8);
        bf16x8 u1 = *(const bf16x8*)(hin + (size_t)s0*128 + 64 + tid8*8);
        if (use_act){
          #pragma unroll
          for (int j = 0; j < 8; ++j){
            agA[j] += fmaxf(fmaf((float)u0[j], scA[j], shA[j]), 0.f);
            agB[j] += fmaxf(fmaf((float)u1[j], scB[j], shB[j]), 0.f);
          }
        } else {
          #pragma unroll
          for (int j = 0; j < 8; ++j){ agA[j] += (float)u0[j]; agB[j] += (float)u1[j]; }
        }
      }
      const float inv = 1.0f / (float)max(c, 1);
      bf16x8 g0, g1;
      #pragma unroll
      for (int j = 0; j < 8; ++j){
        g0[j] = (bf16)(agA[j] * inv);
        g1[j] = (bf16)(agB[j] * inv);
      }
      *(bf16x8*)dst2 = g0;
      *(bf16x8*)dst3 = g1;
    }
    __syncthreads();   // staging complete
    // ---- MFMA K-loop ----
    f32x4 acc[2][2];
    #pragma unroll
    for (int mt = 0; mt < 2; ++mt)
      #pragma unroll
      for (int nt = 0; nt < 2; ++nt)
        #pragma unroll
        for (int r = 0; r < 4; ++r) acc[mt][nt][r] = biasv[nt][r];
    #pragma unroll
    for (int ks = 0; ks < 8; ++ks){
      const int ch = ((ks*4 + quad) ^ (l16 & 7)) * 8;
      bf16x8 af0 = *(const bf16x8*)(alds + l16*256 + ch);
      bf16x8 af1 = *(const bf16x8*)(alds + (l16 + 16)*256 + ch);
      acc[0][0] = __builtin_amdgcn_mfma_f32_16x16x32_bf16(wreg[0][ks], af0, acc[0][0], 0, 0, 0);
      acc[0][1] = __builtin_amdgcn_mfma_f32_16x16x32_bf16(wreg[1][ks], af0, acc[0][1], 0, 0, 0);
      acc[1][0] = __builtin_amdgcn_mfma_f32_16x16x32_bf16(wreg[0][ks], af1, acc[1][0], 0, 0, 0);
      acc[1][1] = __builtin_amdgcn_mfma_f32_16x16x32_bf16(wreg[1][ks], af1, acc[1][1], 0, 0, 0);
    }
    // ---- epilogue ----
    const int grow0 = rbase + l16;
    const int grow1 = grow0 + 16;
    if (cnt[grow0] == 0){
      #pragma unroll
      for (int nt = 0; nt < 2; ++nt)
        #pragma unroll
        for (int r = 0; r < 4; ++r) acc[0][nt][r] -= brv[nt][r];
    }
    if (cnt[grow1] == 0){
      #pragma unroll
      for (int nt = 0; nt < 2; ++nt)
        #pragma unroll
        for (int r = 0; r < 4; ++r) acc[1][nt][r] -= brv[nt][r];
    }
    float s0 = 0.f, s1 = 0.f;
    #pragma unroll
    for (int nt = 0; nt < 2; ++nt)
      #pragma unroll
      for (int r = 0; r < 4; ++r){
        s0 += acc[0][nt][r] * acc[0][nt][r];
        s1 += acc[1][nt][r] * acc[1][nt][r];
      }
    s0 += __shfl_xor(s0, 16); s0 += __shfl_xor(s0, 32);
    s1 += __shfl_xor(s1, 16); s1 += __shfl_xor(s1, 32);
    if (quad == 0){
      rowsq_w[wv][l16]      = s0;
      rowsq_w[wv][l16 + 16] = s1;
    }
    __syncthreads();   // rowsq partials ready (also fences alds reads vs next staging)
    const float scl0 = 1.0f / fmaxf(sqrtf(rowsq_w[0][l16] + rowsq_w[1][l16]
                                        + rowsq_w[2][l16] + rowsq_w[3][l16]), 1e-12f);
    const float scl1 = 1.0f / fmaxf(sqrtf(rowsq_w[0][l16+16] + rowsq_w[1][l16+16]
                                        + rowsq_w[2][l16+16] + rowsq_w[3][l16+16]), 1e-12f);
    #pragma unroll
    for (int nt = 0; nt < 2; ++nt){
      const int col = cbase + nt*16 + quad*4;
      bf16x4 o0, o1;
      #pragma unroll
      for (int r = 0; r < 4; ++r){
        float x0 = acc[0][nt][r] * scl0;
        float x1 = acc[1][nt][r] * scl1;
        o0[r] = (bf16)x0; o1[r] = (bf16)x1;
        cs_acc[nt][r] += x0 + x1;
        cq_acc[nt][r] += x0*x0 + x1*x1;
      }
      *(bf16x4*)(hout + (size_t)grow0*128 + col) = o0;
      *(bf16x4*)(hout + (size_t)grow1*128 + col) = o1;
    }
  }
  // ---- flush BN stats once per block ----
  #pragma unroll
  for (int nt = 0; nt < 2; ++nt)
    #pragma unroll
    for (int r = 0; r < 4; ++r){
      float a = cs_acc[nt][r], b = cq_acc[nt][r];
      #pragma unroll
      for (int off = 1; off < 16; off <<= 1){
        a += __shfl_xor(a, off);
        b += __shfl_xor(b, off);
      }
      if (l16 == 0){
        const int col = cbase + nt*16 + quad*4 + r;
        atomicAdd(&colstats[col], a);
        atomicAdd(&colstats[128 + col], b);
      }
    }
}

// ---------------- BN params; zero stats for next layer ----------------
__global__ void bn_params_kernel(float* __restrict__ cs, const float* __restrict__ gamma,
                                 const float* __restrict__ beta, float* __restrict__ bnp, float Nf){
  int t = threadIdx.x;   // 0..127
  float sum = cs[t], sq = cs[128 + t];
  float mu  = sum / Nf;
  float var = fmaxf(sq / Nf - mu*mu, 0.0f);
  float inv = rsqrtf(var + 1e-5f);
  float scale = gamma[t] * inv;
  bnp[t] = scale;
  bnp[128 + t] = beta[t] - mu * scale;
  cs[t] = 0.0f; cs[128 + t] = 0.0f;
}

// ---------------- pool act(h) per graph: pooledh[g][k] = sum_{n in g} relu(sc*h+sh) ----------------
__global__ __launch_bounds__(256) void poolh_kernel(
    const bf16* __restrict__ h, const float* __restrict__ bnp,
    const int* __restrict__ batch, float* __restrict__ pooledh, int N)
{
  const int t = threadIdx.x;
  const int col = t & 127;
  const int half = t >> 7;
  const float sc = bnp[col];
  const float sh = bnp[128 + col];
  const int chunk = (N + gridDim.x - 1) / gridDim.x;
  const int lo = blockIdx.x * chunk;
  const int hi = min(N, lo + chunk);
  if (lo >= hi) return;
  int gcur = -1;
  float acc = 0.f;
  for (int n = lo + half; n < hi; n += 2){
    int g = batch[n];
    if (g != gcur){
      if (gcur >= 0) atomicAdd(&pooledh[gcur*128 + col], acc);
      gcur = g; acc = 0.f;
    }
    float v = (float)h[(size_t)n*128 + col];
    acc += fmaxf(fmaf(v, sc, sh), 0.f);
  }
  if (gcur >= 0) atomicAdd(&pooledh[gcur*128 + col], acc);
}

// ---------------- final: out[g] = log_softmax(pooledh[g] @ Wc^T + cnt_g*bc) ----------------
__global__ void lsm_kernel(const float* __restrict__ ph, const float* __restrict__ Wc,
                           const float* __restrict__ bc, const int* __restrict__ batch,
                           int N, float* __restrict__ out)
{
  __shared__ int cntg_s;
  const int g = blockIdx.x;
  const int t = threadIdx.x;   // 64 threads = one wave
  if (t == 0){
    int lo = 0, hi = N;
    while (lo < hi){ int mid = (lo + hi) >> 1; if (batch[mid] < g) lo = mid + 1; else hi = mid; }
    int lo2 = lo, hi2 = N;
    while (lo2 < hi2){ int mid = (lo2 + hi2) >> 1; if (batch[mid] < g + 1) lo2 = mid + 1; else hi2 = mid; }
    cntg_s = lo2 - lo;
  }
  __syncthreads();
  float z = -3.0e38f;
  if (t < 40){
    float s = (float)cntg_s * bc[t];
    const float* phg = ph + g*128;
    const float* w = Wc + t*128;
    for (int k = 0; k < 128; k += 4){
      float4 a = *(const float4*)(phg + k);
      float4 b = *(const float4*)(w + k);
      s = fmaf(a.x, b.x, s); s = fmaf(a.y, b.y, s);
      s = fmaf(a.z, b.z, s); s = fmaf(a.w, b.w, s);
    }
    z = s;
  }
  float mx = z;
  #pragma unroll
  for (int off = 32; off; off >>= 1) mx = fmaxf(mx, __shfl_xor(mx, off));
  float ex = (t < 40) ? expf(z - mx) : 0.0f;
  float sum = ex;
  #pragma unroll
  for (int off = 32; off; off >>= 1) sum += __shfl_xor(sum, off);
  float lse = mx + logf(sum);
  if (t < 40) out[g*40 + t] = z - lse;
}

extern "C" void kernel_launch(void* const* d_in, const int* in_sizes, int n_in,
                              void* d_out, int out_size, void* d_ws, size_t ws_size,
                              hipStream_t stream)
{
  const float* x    = (const float*)d_in[0];
  const int*   ei   = (const int*)d_in[1];
  const int*   batch= (const int*)d_in[2];
  const float* Wl   = (const float*)d_in[3];
  const float* bl   = (const float*)d_in[4];
  const float* Wr   = (const float*)d_in[5];
  const float* br   = (const float*)d_in[6];
  const float* gamma= (const float*)d_in[7];
  const float* beta = (const float*)d_in[8];
  const float* W1   = (const float*)d_in[9];
  const float* b1   = (const float*)d_in[10];
  const float* W2   = (const float*)d_in[11];
  const float* b2   = (const float*)d_in[12];
  float* out = (float*)d_out;

  const int N = in_sizes[0] / 128;
  const int E = in_sizes[1] / 2;
  const int G = out_size / 40;

  char* p = (char*)d_ws;
  auto carve = [&](size_t bytes)->char*{ char* r = p; p += alignup(bytes); return r; };
  bf16*  xbf      = (bf16*)carve((size_t)N * 128 * 2);
  bf16*  hA       = (bf16*)carve((size_t)N * 128 * 2);
  bf16*  hB       = (bf16*)carve((size_t)N * 128 * 2);
  int*   esrc     = (int*)carve((size_t)E * 4);
  int*   rs       = (int*)carve((size_t)N * 4);
  int*   cnt      = (int*)carve((size_t)N * 4);
  int*   cur      = (int*)carve((size_t)N * 4);
  int*   bsum     = (int*)carve(512 * 4);
  float* colstats = (float*)carve(256 * 4);
  float* bnp      = (float*)carve(256 * 4);
  float* Wc       = (float*)carve(40 * 128 * 4);
  float* bc       = (float*)carve(40 * 4);
  bf16*  Wbig     = (bf16*)carve((size_t)3 * 128 * 256 * 2);
  float* pooledh  = (float*)carve((size_t)G * 128 * 4);

  hipMemsetAsync(cnt, 0, (size_t)N * 4, stream);
  hipMemsetAsync(colstats, 0, 256 * 4, stream);
  hipMemsetAsync(pooledh, 0, (size_t)G * 128 * 4, stream);

  const int eb = (E + 255) / 256;
  const int nb = (N + 255) / 256;
  count_kernel<<<eb, 256, 0, stream>>>(ei, E, cnt);
  scan1_kernel<<<nb, 256, 0, stream>>>(cnt, rs, bsum, N);
  scan2_kernel<<<1, 512, 0, stream>>>(bsum, nb);
  scan3_kernel<<<nb, 256, 0, stream>>>(rs, bsum, cur, N);
  fill_kernel<<<eb, 256, 0, stream>>>(ei, E, cur, esrc);
  xbf_kernel<<<(N*16 + 255)/256, 256, 0, stream>>>(x, xbf, N*16);
  wc_kernel<<<40, 128, 0, stream>>>(W1, b1, W2, b2, Wc, bc);
  wprep_kernel<<<(3*128*256 + 255)/256, 256, 0, stream>>>(Wl, Wr, Wbig);

  const float Nf = (float)N;
  // ping-pong: l0 xbf->hA, l1 hA->hB, l2 hB->hA  (hin never aliases hout)
  const bf16* ins[3]  = {xbf, hA, hB};
  bf16*       outs[3] = {hA,  hB, hA};
  for (int l = 0; l < 3; ++l){
    gemm_fused<<<768, 256, 0, stream>>>(ins[l], bnp, (l > 0) ? 1 : 0,
                                        Wbig + (size_t)l * 32768, bl + l*128, br + l*128,
                                        rs, cnt, esrc, outs[l], colstats, N);
    bn_params_kernel<<<1, 128, 0, stream>>>(colstats, gamma + l*128, beta + l*128, bnp, Nf);
  }
  poolh_kernel<<<1024, 256, 0, stream>>>(hA, bnp, batch, pooledh, N);
  lsm_kernel<<<G, 64, 0, stream>>>(pooledh, Wc, bc, batch, N, out);
}